// Round 1
// baseline (1781.161 us; speedup 1.0000x reference)
//
#include <hip/hip_runtime.h>
#include <math.h>

#define D_FEAT 512
#define HID 64
#define CLS 16

// ---------- degree / normalization ----------
__global__ __launch_bounds__(256) void k_deg_init(float* __restrict__ deg, int N) {
  int i = blockIdx.x * 256 + threadIdx.x;
  if (i < N) deg[i] = 1.0f;  // self-loop
}

__global__ __launch_bounds__(256) void k_deg_count(const int* __restrict__ dst, float* __restrict__ deg, int E) {
  int e = blockIdx.x * 256 + threadIdx.x;
  if (e < E) atomicAdd(&deg[dst[e]], 1.0f);
}

__global__ __launch_bounds__(256) void k_dinv(float* __restrict__ deg, int N) {
  int i = blockIdx.x * 256 + threadIdx.x;
  if (i < N) deg[i] = rsqrtf(deg[i]);  // deg >= 1 always
}

// ---------- GEMM1: h[N][64] = x[N][512] @ W1[512][64] ----------
// one wave per 8 rows; lane = output column; k vectorized by float4 on x
__global__ __launch_bounds__(256) void k_gemm1(const float* __restrict__ x, const float* __restrict__ W1,
                                               float* __restrict__ h, int N) {
  int gwave = (blockIdx.x * 256 + threadIdx.x) >> 6;
  int lane = threadIdx.x & 63;
  int i0 = gwave * 8;
  if (i0 >= N) return;
  float acc[8] = {0.f, 0.f, 0.f, 0.f, 0.f, 0.f, 0.f, 0.f};
  for (int k0 = 0; k0 < D_FEAT; k0 += 4) {
    float w0 = W1[(k0 + 0) * HID + lane];
    float w1 = W1[(k0 + 1) * HID + lane];
    float w2 = W1[(k0 + 2) * HID + lane];
    float w3 = W1[(k0 + 3) * HID + lane];
#pragma unroll
    for (int r = 0; r < 8; r++) {
      int ir = i0 + r;
      if (ir >= N) ir = N - 1;  // clamp (N%8==0 in practice; keeps OOB safe)
      const float4 xv = *reinterpret_cast<const float4*>(&x[(size_t)ir * D_FEAT + k0]);
      acc[r] = fmaf(xv.x, w0, acc[r]);
      acc[r] = fmaf(xv.y, w1, acc[r]);
      acc[r] = fmaf(xv.z, w2, acc[r]);
      acc[r] = fmaf(xv.w, w3, acc[r]);
    }
  }
#pragma unroll
  for (int r = 0; r < 8; r++) {
    int ir = i0 + r;
    if (ir < N) h[(size_t)ir * HID + lane] = acc[r];
  }
}

// ---------- aggregation 1 (64 features) ----------
// self-loop term also serves as the buffer initializer (ws is poisoned 0xAA)
__global__ __launch_bounds__(256) void k_agg1_self(const float* __restrict__ h, const float* __restrict__ dinv,
                                                   float* __restrict__ agg, int N) {
  size_t t = (size_t)blockIdx.x * 256 + threadIdx.x;
  if (t >= (size_t)N * HID) return;
  int i = (int)(t >> 6);
  float di = dinv[i];
  agg[t] = h[t] * di * di;
}

// one wave per edge, lane = feature
__global__ __launch_bounds__(256) void k_agg1_edges(const int* __restrict__ src, const int* __restrict__ dst,
                                                    const float* __restrict__ dinv, const float* __restrict__ h,
                                                    float* __restrict__ agg, int E) {
  int wid = (blockIdx.x * 256 + threadIdx.x) >> 6;
  int lane = threadIdx.x & 63;
  if (wid >= E) return;
  int s = src[wid];
  int d = dst[wid];
  float coef = dinv[s] * dinv[d];
  atomicAdd(&agg[(size_t)d * HID + lane], h[(size_t)s * HID + lane] * coef);
}

// ---------- bias + relu -> h1 ----------
__global__ __launch_bounds__(256) void k_relu_bias(const float* __restrict__ agg, const float* __restrict__ b1,
                                                   float* __restrict__ h1, int N) {
  size_t t = (size_t)blockIdx.x * 256 + threadIdx.x;
  if (t >= (size_t)N * HID) return;
  int j = (int)(t & 63);
  float v = agg[t] + b1[j];
  h1[t] = v > 0.f ? v : 0.f;
}

// ---------- GEMM2: p[N][16] = h1[N][64] @ W2[64][16] ----------
// thread per output element; j vectorized by 4 on h1
__global__ __launch_bounds__(256) void k_gemm2(const float* __restrict__ h1, const float* __restrict__ W2,
                                               float* __restrict__ p, int N) {
  size_t t = (size_t)blockIdx.x * 256 + threadIdx.x;
  if (t >= (size_t)N * CLS) return;
  int i = (int)(t >> 4);
  int c = (int)(t & 15);
  float acc = 0.f;
#pragma unroll
  for (int j = 0; j < HID; j += 4) {
    const float4 hv = *reinterpret_cast<const float4*>(&h1[(size_t)i * HID + j]);
    acc = fmaf(hv.x, W2[(j + 0) * CLS + c], acc);
    acc = fmaf(hv.y, W2[(j + 1) * CLS + c], acc);
    acc = fmaf(hv.z, W2[(j + 2) * CLS + c], acc);
    acc = fmaf(hv.w, W2[(j + 3) * CLS + c], acc);
  }
  p[t] = acc;
}

// ---------- aggregation 2 (16 features) into d_out ----------
__global__ __launch_bounds__(256) void k_agg2_self(const float* __restrict__ p, const float* __restrict__ dinv,
                                                   float* __restrict__ out, int N) {
  size_t t = (size_t)blockIdx.x * 256 + threadIdx.x;
  if (t >= (size_t)N * CLS) return;
  int i = (int)(t >> 4);
  float di = dinv[i];
  out[t] = p[t] * di * di;
}

// 4 edges per wave, 16 lanes per edge
__global__ __launch_bounds__(256) void k_agg2_edges(const int* __restrict__ src, const int* __restrict__ dst,
                                                    const float* __restrict__ dinv, const float* __restrict__ p,
                                                    float* __restrict__ out, int E) {
  size_t t = (size_t)blockIdx.x * 256 + threadIdx.x;
  int e = (int)(t >> 4);
  int c = (int)(t & 15);
  if (e >= E) return;
  int s = src[e];
  int d = dst[e];
  float coef = dinv[s] * dinv[d];
  atomicAdd(&out[(size_t)d * CLS + c], p[(size_t)s * CLS + c] * coef);
}

// ---------- bias + log_softmax in place on d_out ----------
__global__ __launch_bounds__(256) void k_lsm(float* __restrict__ out, const float* __restrict__ b2, int N) {
  int i = blockIdx.x * 256 + threadIdx.x;
  if (i >= N) return;
  float v[16];
#pragma unroll
  for (int q = 0; q < 4; q++) {
    float4 tv = *reinterpret_cast<const float4*>(&out[(size_t)i * CLS + q * 4]);
    v[q * 4 + 0] = tv.x + b2[q * 4 + 0];
    v[q * 4 + 1] = tv.y + b2[q * 4 + 1];
    v[q * 4 + 2] = tv.z + b2[q * 4 + 2];
    v[q * 4 + 3] = tv.w + b2[q * 4 + 3];
  }
  float m = v[0];
#pragma unroll
  for (int c = 1; c < 16; c++) m = fmaxf(m, v[c]);
  float s = 0.f;
#pragma unroll
  for (int c = 0; c < 16; c++) s += expf(v[c] - m);
  float lse = logf(s);
#pragma unroll
  for (int q = 0; q < 4; q++) {
    float4 tv;
    tv.x = v[q * 4 + 0] - m - lse;
    tv.y = v[q * 4 + 1] - m - lse;
    tv.z = v[q * 4 + 2] - m - lse;
    tv.w = v[q * 4 + 3] - m - lse;
    *reinterpret_cast<float4*>(&out[(size_t)i * CLS + q * 4]) = tv;
  }
}

extern "C" void kernel_launch(void* const* d_in, const int* in_sizes, int n_in,
                              void* d_out, int out_size, void* d_ws, size_t ws_size,
                              hipStream_t stream) {
  const float* x = (const float*)d_in[0];
  const int* ei = (const int*)d_in[1];
  const float* W1 = (const float*)d_in[2];
  const float* b1 = (const float*)d_in[3];
  const float* W2 = (const float*)d_in[4];
  const float* b2 = (const float*)d_in[5];
  float* out = (float*)d_out;

  const int N = in_sizes[0] / D_FEAT;
  const int E = in_sizes[1] / 2;
  const int* src = ei;
  const int* dst = ei + E;

  // workspace layout (floats): [deg/dinv: N (padded)] [h / h1: N*64] [agg1 / p: N*64]
  float* deg = (float*)d_ws;
  size_t nal = ((size_t)N + 255) & ~(size_t)255;
  float* h = deg + nal;            // h, then reused as h1 (relu output)
  float* agg1 = h + (size_t)N * HID;  // agg1, then reused as p
  float* p = agg1;

  // 1. degree + dinv
  k_deg_init<<<(N + 255) / 256, 256, 0, stream>>>(deg, N);
  k_deg_count<<<(E + 255) / 256, 256, 0, stream>>>(dst, deg, E);
  k_dinv<<<(N + 255) / 256, 256, 0, stream>>>(deg, N);

  // 2. h = x @ W1
  {
    int waves = (N + 7) / 8;
    int blocks = (waves * 64 + 255) / 256;
    k_gemm1<<<blocks, 256, 0, stream>>>(x, W1, h, N);
  }

  // 3. agg1 = D^-1/2 (A+I) D^-1/2 h
  {
    size_t tt = (size_t)N * HID;
    k_agg1_self<<<(unsigned)((tt + 255) / 256), 256, 0, stream>>>(h, deg, agg1, N);
    int blocks = (E + 3) / 4;  // 4 waves/block, 1 edge/wave
    k_agg1_edges<<<blocks, 256, 0, stream>>>(src, dst, deg, h, agg1, E);
  }

  // 4. h1 = relu(agg1 + b1)  (into h buffer)
  {
    size_t tt = (size_t)N * HID;
    k_relu_bias<<<(unsigned)((tt + 255) / 256), 256, 0, stream>>>(agg1, b1, h, N);
  }

  // 5. p = h1 @ W2  (into agg1 buffer)
  {
    size_t tt = (size_t)N * CLS;
    k_gemm2<<<(unsigned)((tt + 255) / 256), 256, 0, stream>>>(h, W2, p, N);
  }

  // 6. agg2 into d_out
  {
    size_t tt = (size_t)N * CLS;
    k_agg2_self<<<(unsigned)((tt + 255) / 256), 256, 0, stream>>>(p, deg, out, N);
    size_t et = (size_t)E * CLS;
    k_agg2_edges<<<(unsigned)((et + 255) / 256), 256, 0, stream>>>(src, dst, deg, p, out, E);
  }

  // 7. bias + log_softmax
  k_lsm<<<(N + 255) / 256, 256, 0, stream>>>(out, b2, N);
}

// Round 3
// 1461.275 us; speedup vs baseline: 1.2189x; 1.2189x over previous
//
#include <hip/hip_runtime.h>
#include <math.h>

#define D_FEAT 512
#define HID 64
#define CLS 16

// ---------- utility ----------
__global__ __launch_bounds__(256) void k_zero_u32(unsigned* __restrict__ p, int n) {
  int i = blockIdx.x * 256 + threadIdx.x;
  if (i < n) p[i] = 0u;
}

// ---------- histogram of dst ----------
__global__ __launch_bounds__(256) void k_hist(const int* __restrict__ dst, unsigned* __restrict__ cnt, int E) {
  int e = blockIdx.x * 256 + threadIdx.x;
  if (e < E) atomicAdd(&cnt[dst[e]], 1u);
}

// ---------- dinv[i] = rsqrt(cnt[i] + 1)  (self-loop) ----------
__global__ __launch_bounds__(256) void k_dinv(const unsigned* __restrict__ cnt, float* __restrict__ dinv, int N) {
  int i = blockIdx.x * 256 + threadIdx.x;
  if (i < N) dinv[i] = rsqrtf((float)(cnt[i] + 1u));
}

// ---------- single-block exclusive scan of cnt -> off (off[N] = E) ----------
// per-wave shfl inclusive scan, LDS for the 16 wave totals; 2 syncs per 1024-chunk
__global__ __launch_bounds__(1024) void k_scan(const unsigned* __restrict__ cnt, unsigned* __restrict__ off, int N) {
  __shared__ unsigned wtot[16];
  const int t = threadIdx.x;
  const int wav = t >> 6, lane = t & 63;
  unsigned carry = 0;
  for (int base = 0; base < N; base += 1024) {
    int i = base + t;
    unsigned v = (i < N) ? cnt[i] : 0u;
    unsigned x = v;
#pragma unroll
    for (int o = 1; o < 64; o <<= 1) {
      unsigned y = __shfl_up(x, o);
      if (lane >= o) x += y;
    }
    if (lane == 63) wtot[wav] = x;
    __syncthreads();
    unsigned wpre = 0, tot = 0;
#pragma unroll
    for (int w = 0; w < 16; w++) {
      unsigned tw = wtot[w];
      if (w < wav) wpre += tw;
      tot += tw;
    }
    if (i < N) off[i] = carry + wpre + (x - v);  // exclusive = carry + wave prefix + (incl - v)
    carry += tot;
    __syncthreads();  // protect wtot before next chunk
  }
  if (t == 0) off[N] = carry;
}

// ---------- scatter src into CSR order (cursor = re-zeroed cnt) ----------
__global__ __launch_bounds__(256) void k_scatter(const int* __restrict__ src, const int* __restrict__ dst,
                                                 const unsigned* __restrict__ off, unsigned* __restrict__ cur,
                                                 unsigned* __restrict__ ssrc, int E) {
  int e = blockIdx.x * 256 + threadIdx.x;
  if (e >= E) return;
  int d = dst[e];
  unsigned pos = off[d] + atomicAdd(&cur[d], 1u);
  ssrc[pos] = (unsigned)src[e];
}

// ---------- GEMM1: h[N][64] = x[N][512] @ W1[512][64] ----------
__global__ __launch_bounds__(256) void k_gemm1(const float* __restrict__ x, const float* __restrict__ W1,
                                               float* __restrict__ h, int N) {
  int gwave = (blockIdx.x * 256 + threadIdx.x) >> 6;
  int lane = threadIdx.x & 63;
  int i0 = gwave * 8;
  if (i0 >= N) return;
  float acc[8] = {0.f, 0.f, 0.f, 0.f, 0.f, 0.f, 0.f, 0.f};
  for (int k0 = 0; k0 < D_FEAT; k0 += 4) {
    float w0 = W1[(k0 + 0) * HID + lane];
    float w1 = W1[(k0 + 1) * HID + lane];
    float w2 = W1[(k0 + 2) * HID + lane];
    float w3 = W1[(k0 + 3) * HID + lane];
#pragma unroll
    for (int r = 0; r < 8; r++) {
      int ir = i0 + r;
      if (ir >= N) ir = N - 1;
      const float4 xv = *reinterpret_cast<const float4*>(&x[(size_t)ir * D_FEAT + k0]);
      acc[r] = fmaf(xv.x, w0, acc[r]);
      acc[r] = fmaf(xv.y, w1, acc[r]);
      acc[r] = fmaf(xv.z, w2, acc[r]);
      acc[r] = fmaf(xv.w, w3, acc[r]);
    }
  }
#pragma unroll
  for (int r = 0; r < 8; r++) {
    int ir = i0 + r;
    if (ir < N) h[(size_t)ir * HID + lane] = acc[r];
  }
}

// ---------- fused agg1 + bias + ReLU + GEMM2: one wave per dst node ----------
// wave computes h1-row (64 wide) in registers, then projects to 16 classes in-wave.
__global__ __launch_bounds__(256) void k_agg1_g2(const float* __restrict__ h, const float* __restrict__ dinv,
                                                 const unsigned* __restrict__ off, const unsigned* __restrict__ ssrc,
                                                 const float* __restrict__ b1, const float* __restrict__ W2,
                                                 float* __restrict__ p, int N) {
  __shared__ float sh[4][64];
  const int wav = threadIdx.x >> 6;
  const int lane = threadIdx.x & 63;
  const int node = (blockIdx.x * 256 + threadIdx.x) >> 6;
  const bool valid = node < N;

  float v = 0.f;
  if (valid) {
    float di = dinv[node];
    float acc = h[(size_t)node * HID + lane] * di;
    unsigned e0 = off[node], e1 = off[node + 1];
    for (unsigned e = e0; e < e1; ++e) {
      int s = (int)ssrc[e];
      acc = fmaf(h[(size_t)s * HID + lane], dinv[s], acc);
    }
    v = fmaxf(fmaf(acc, di, b1[lane]), 0.f);  // relu(agg*di + b1)
  }
  sh[wav][lane] = v;
  __syncthreads();

  // p[node][c] = sum_j h1[j] * W2[j][c]; c = lane&15, j-group = lane>>4
  const int grp = lane >> 4, c = lane & 15;
  float partial = 0.f;
  const float* hv = &sh[wav][grp * 16];
#pragma unroll
  for (int k = 0; k < 16; k++) partial = fmaf(hv[k], W2[(grp * 16 + k) * CLS + c], partial);
  partial += __shfl_xor(partial, 16);
  partial += __shfl_xor(partial, 32);
  if (valid && lane < 16) p[(size_t)node * CLS + c] = partial;
}

// ---------- fused agg2 + bias + log_softmax: 16 lanes per node ----------
__global__ __launch_bounds__(256) void k_agg2(const float* __restrict__ p, const float* __restrict__ dinv,
                                              const unsigned* __restrict__ off, const unsigned* __restrict__ ssrc,
                                              const float* __restrict__ b2, float* __restrict__ out, int N) {
  int t = blockIdx.x * 256 + threadIdx.x;
  int node = t >> 4;
  int c = t & 15;
  if (node >= N) return;
  float di = dinv[node];
  float acc = p[(size_t)node * CLS + c] * di;
  unsigned e0 = off[node], e1 = off[node + 1];
  for (unsigned e = e0; e < e1; ++e) {
    int s = (int)ssrc[e];
    acc = fmaf(p[(size_t)s * CLS + c], dinv[s], acc);
  }
  float v = fmaf(acc, di, b2[c]);
  float m = v;
#pragma unroll
  for (int o = 8; o >= 1; o >>= 1) m = fmaxf(m, __shfl_xor(m, o, 16));
  float ex = expf(v - m);
  float s = ex;
#pragma unroll
  for (int o = 8; o >= 1; o >>= 1) s += __shfl_xor(s, o, 16);
  out[(size_t)node * CLS + c] = v - m - logf(s);
}

extern "C" void kernel_launch(void* const* d_in, const int* in_sizes, int n_in,
                              void* d_out, int out_size, void* d_ws, size_t ws_size,
                              hipStream_t stream) {
  const float* x = (const float*)d_in[0];
  const int* ei = (const int*)d_in[1];
  const float* W1 = (const float*)d_in[2];
  const float* b1 = (const float*)d_in[3];
  const float* W2 = (const float*)d_in[4];
  const float* b2 = (const float*)d_in[5];
  float* out = (float*)d_out;

  const int N = in_sizes[0] / D_FEAT;
  const int E = in_sizes[1] / 2;
  const int* src = ei;
  const int* dst = ei + E;

  // workspace (4-byte words): [cnt/cursor: nal][off: nal][dinv: nal][ssrc: Eal][h: N*64][p: N*16]
  // total ~46 MB for N=100k, E=3.2M (below round-0's proven 51.6 MB usage)
  size_t nal = ((size_t)N + 1 + 255) & ~(size_t)255;
  size_t Eal = ((size_t)E + 255) & ~(size_t)255;
  unsigned* cnt = (unsigned*)d_ws;
  unsigned* off = cnt + nal;
  float* dinv = (float*)(off + nal);
  unsigned* ssrc = (unsigned*)(dinv + nal);
  float* h = (float*)(ssrc + Eal);
  float* p = h + (size_t)N * HID;

  int nb_N = (N + 255) / 256;
  int nb_E = (E + 255) / 256;

  // 1. CSR build + dinv
  k_zero_u32<<<nb_N, 256, 0, stream>>>(cnt, N);
  k_hist<<<nb_E, 256, 0, stream>>>(dst, cnt, E);
  k_dinv<<<nb_N, 256, 0, stream>>>(cnt, dinv, N);
  k_scan<<<1, 1024, 0, stream>>>(cnt, off, N);
  k_zero_u32<<<nb_N, 256, 0, stream>>>(cnt, N);  // reuse as scatter cursor
  k_scatter<<<nb_E, 256, 0, stream>>>(src, dst, off, cnt, ssrc, E);

  // 2. h = x @ W1
  {
    int waves = (N + 7) / 8;
    int blocks = (waves * 64 + 255) / 256;
    k_gemm1<<<blocks, 256, 0, stream>>>(x, W1, h, N);
  }

  // 3+4. p = relu(D^-1/2(A+I)D^-1/2 h + b1) @ W2   (fused, no h1 buffer)
  {
    long long tt = (long long)N * 64;
    k_agg1_g2<<<(unsigned)((tt + 255) / 256), 256, 0, stream>>>(h, dinv, off, ssrc, b1, W2, p, N);
  }

  // 5. out = log_softmax(D^-1/2(A+I)D^-1/2 p + b2)
  {
    long long tt = (long long)N * CLS;
    k_agg2<<<(unsigned)((tt + 255) / 256), 256, 0, stream>>>(p, dinv, off, ssrc, b2, out, N);
  }
}

// Round 4
// 971.538 us; speedup vs baseline: 1.8333x; 1.5041x over previous
//
#include <hip/hip_runtime.h>
#include <math.h>

#define D_FEAT 512
#define HID 64
#define CLS 16
#define BR 32  // rows per block in gemm1

// ---------- utility ----------
__global__ __launch_bounds__(256) void k_zero_u32(unsigned* __restrict__ p, int n) {
  int i = blockIdx.x * 256 + threadIdx.x;
  if (i < n) p[i] = 0u;
}

// ---------- histogram of dst ----------
__global__ __launch_bounds__(256) void k_hist(const int* __restrict__ dst, unsigned* __restrict__ cnt, int E) {
  int e = blockIdx.x * 256 + threadIdx.x;
  if (e < E) atomicAdd(&cnt[dst[e]], 1u);
}

// ---------- dinv[i] = rsqrt(cnt[i] + 1)  (self-loop) ----------
__global__ __launch_bounds__(256) void k_dinv(const unsigned* __restrict__ cnt, float* __restrict__ dinv, int N) {
  int i = blockIdx.x * 256 + threadIdx.x;
  if (i < N) dinv[i] = rsqrtf((float)(cnt[i] + 1u));
}

// ---------- hierarchical exclusive scan ----------
// pass 1: per-block exclusive scan + block totals
__global__ __launch_bounds__(256) void k_scan1(const unsigned* __restrict__ cnt, unsigned* __restrict__ off,
                                               unsigned* __restrict__ btot, int N) {
  __shared__ unsigned wtot[4];
  const int t = threadIdx.x, wav = t >> 6, lane = t & 63;
  int i = blockIdx.x * 256 + t;
  unsigned v = (i < N) ? cnt[i] : 0u;
  unsigned xx = v;
#pragma unroll
  for (int o = 1; o < 64; o <<= 1) {
    unsigned y = __shfl_up(xx, o);
    if (lane >= o) xx += y;
  }
  if (lane == 63) wtot[wav] = xx;
  __syncthreads();
  unsigned wpre = 0, tot = 0;
#pragma unroll
  for (int w = 0; w < 4; w++) {
    unsigned tw = wtot[w];
    if (w < wav) wpre += tw;
    tot += tw;
  }
  if (i < N) off[i] = wpre + (xx - v);
  if (t == 0) btot[blockIdx.x] = tot;
}

// pass 2: single-block exclusive scan of block totals (loops if nb > 256)
__global__ __launch_bounds__(256) void k_scan2(unsigned* __restrict__ btot, int nb) {
  __shared__ unsigned wtot[4];
  const int t = threadIdx.x, wav = t >> 6, lane = t & 63;
  unsigned carry = 0;
  for (int base = 0; base < nb; base += 256) {
    int i = base + t;
    unsigned v = (i < nb) ? btot[i] : 0u;
    unsigned xx = v;
#pragma unroll
    for (int o = 1; o < 64; o <<= 1) {
      unsigned y = __shfl_up(xx, o);
      if (lane >= o) xx += y;
    }
    if (lane == 63) wtot[wav] = xx;
    __syncthreads();
    unsigned wpre = 0, tot = 0;
#pragma unroll
    for (int w = 0; w < 4; w++) {
      unsigned tw = wtot[w];
      if (w < wav) wpre += tw;
      tot += tw;
    }
    if (i < nb) btot[i] = carry + wpre + (xx - v);
    carry += tot;
    __syncthreads();
  }
}

// pass 3: add block prefix; write off[N] = E
__global__ __launch_bounds__(256) void k_scan3(unsigned* __restrict__ off, const unsigned* __restrict__ btot,
                                               int N, int E) {
  int i = blockIdx.x * 256 + threadIdx.x;
  if (i < N) off[i] += btot[blockIdx.x];
  if (i == 0) off[N] = (unsigned)E;
}

// ---------- scatter src into CSR order (cursor = re-zeroed cnt) ----------
__global__ __launch_bounds__(256) void k_scatter(const int* __restrict__ src, const int* __restrict__ dst,
                                                 const unsigned* __restrict__ off, unsigned* __restrict__ cur,
                                                 unsigned* __restrict__ ssrc, int E) {
  int e = blockIdx.x * 256 + threadIdx.x;
  if (e >= E) return;
  int d = dst[e];
  unsigned pos = off[d] + atomicAdd(&cur[d], 1u);
  ssrc[pos] = (unsigned)src[e];
}

// ---------- GEMM1: h[N][64] = x[N][512] @ W1[512][64] ----------
// block: 256 thr = 4 waves, 32 rows. x tile staged in LDS (coalesced), lane = col,
// W1 chunked 32-k into registers (32 independent coalesced loads per chunk).
__global__ __launch_bounds__(256) void k_gemm1(const float* __restrict__ x, const float* __restrict__ W1,
                                               float* __restrict__ h, int N) {
  __shared__ float4 xs[BR][D_FEAT / 4];  // 32 x 128 float4 = 64 KB
  const int t = threadIdx.x;
  const int i0 = blockIdx.x * BR;
  // stage: 4096 float4s, 16 per thread, coalesced
#pragma unroll
  for (int j = 0; j < 16; j++) {
    int f = t + 256 * j;
    int row = f >> 7, c4 = f & 127;
    int ir = i0 + row;
    if (ir >= N) ir = N - 1;
    xs[row][c4] = *reinterpret_cast<const float4*>(&x[(size_t)ir * D_FEAT + c4 * 4]);
  }
  __syncthreads();

  const int wav = t >> 6, lane = t & 63;
  const int r0 = wav * 8;
  float acc[8] = {0.f, 0.f, 0.f, 0.f, 0.f, 0.f, 0.f, 0.f};
#pragma unroll 2
  for (int k0 = 0; k0 < D_FEAT; k0 += 32) {
    float w[32];
#pragma unroll
    for (int q = 0; q < 32; q++) w[q] = W1[(k0 + q) * HID + lane];
#pragma unroll
    for (int q4 = 0; q4 < 8; q4++) {
#pragma unroll
      for (int r = 0; r < 8; r++) {
        float4 xv = xs[r0 + r][(k0 >> 2) + q4];
        acc[r] = fmaf(xv.x, w[q4 * 4 + 0], acc[r]);
        acc[r] = fmaf(xv.y, w[q4 * 4 + 1], acc[r]);
        acc[r] = fmaf(xv.z, w[q4 * 4 + 2], acc[r]);
        acc[r] = fmaf(xv.w, w[q4 * 4 + 3], acc[r]);
      }
    }
  }
#pragma unroll
  for (int r = 0; r < 8; r++) {
    int ir = i0 + r0 + r;
    if (ir < N) h[(size_t)ir * HID + lane] = acc[r];
  }
}

// ---------- fused agg1 + bias + ReLU + GEMM2: one wave per dst node ----------
__global__ __launch_bounds__(256) void k_agg1_g2(const float* __restrict__ h, const float* __restrict__ dinv,
                                                 const unsigned* __restrict__ off, const unsigned* __restrict__ ssrc,
                                                 const float* __restrict__ b1, const float* __restrict__ W2,
                                                 float* __restrict__ p, int N) {
  __shared__ float sh[4][64];
  const int wav = threadIdx.x >> 6;
  const int lane = threadIdx.x & 63;
  const int node = (blockIdx.x * 256 + threadIdx.x) >> 6;
  const bool valid = node < N;

  float v = 0.f;
  if (valid) {
    float di = dinv[node];
    float acc = h[(size_t)node * HID + lane] * di;
    unsigned e0 = off[node], e1 = off[node + 1];
    unsigned e = e0;
    // unroll-8: 8 independent gather chains in flight
    for (; e + 8 <= e1; e += 8) {
      unsigned sv[8];
      float dv[8], hv[8];
#pragma unroll
      for (int j = 0; j < 8; j++) sv[j] = ssrc[e + j];
#pragma unroll
      for (int j = 0; j < 8; j++) dv[j] = dinv[sv[j]];
#pragma unroll
      for (int j = 0; j < 8; j++) hv[j] = h[(size_t)sv[j] * HID + lane];
#pragma unroll
      for (int j = 0; j < 8; j++) acc = fmaf(hv[j], dv[j], acc);
    }
    for (; e < e1; ++e) {
      unsigned s = ssrc[e];
      acc = fmaf(h[(size_t)s * HID + lane], dinv[s], acc);
    }
    v = fmaxf(fmaf(acc, di, b1[lane]), 0.f);
  }
  sh[wav][lane] = v;
  __syncthreads();

  const int grp = lane >> 4, c = lane & 15;
  float partial = 0.f;
  const float* hv = &sh[wav][grp * 16];
#pragma unroll
  for (int k = 0; k < 16; k++) partial = fmaf(hv[k], W2[(grp * 16 + k) * CLS + c], partial);
  partial += __shfl_xor(partial, 16);
  partial += __shfl_xor(partial, 32);
  if (valid && lane < 16) p[(size_t)node * CLS + c] = partial;
}

// ---------- fused agg2 + bias + log_softmax: 16 lanes per node ----------
__global__ __launch_bounds__(256) void k_agg2(const float* __restrict__ p, const float* __restrict__ dinv,
                                              const unsigned* __restrict__ off, const unsigned* __restrict__ ssrc,
                                              const float* __restrict__ b2, float* __restrict__ out, int N) {
  int t = blockIdx.x * 256 + threadIdx.x;
  int node = t >> 4;
  int c = t & 15;
  if (node >= N) return;
  float di = dinv[node];
  float acc = p[(size_t)node * CLS + c] * di;
  unsigned e0 = off[node], e1 = off[node + 1];
  unsigned e = e0;
  for (; e + 8 <= e1; e += 8) {
    unsigned sv[8];
    float dv[8], pv[8];
#pragma unroll
    for (int j = 0; j < 8; j++) sv[j] = ssrc[e + j];
#pragma unroll
    for (int j = 0; j < 8; j++) dv[j] = dinv[sv[j]];
#pragma unroll
    for (int j = 0; j < 8; j++) pv[j] = p[(size_t)sv[j] * CLS + c];
#pragma unroll
    for (int j = 0; j < 8; j++) acc = fmaf(pv[j], dv[j], acc);
  }
  for (; e < e1; ++e) {
    unsigned s = ssrc[e];
    acc = fmaf(p[(size_t)s * CLS + c], dinv[s], acc);
  }
  float v = fmaf(acc, di, b2[c]);
  float m = v;
#pragma unroll
  for (int o = 8; o >= 1; o >>= 1) m = fmaxf(m, __shfl_xor(m, o, 16));
  float ex = expf(v - m);
  float s = ex;
#pragma unroll
  for (int o = 8; o >= 1; o >>= 1) s += __shfl_xor(s, o, 16);
  out[(size_t)node * CLS + c] = v - m - logf(s);
}

extern "C" void kernel_launch(void* const* d_in, const int* in_sizes, int n_in,
                              void* d_out, int out_size, void* d_ws, size_t ws_size,
                              hipStream_t stream) {
  const float* x = (const float*)d_in[0];
  const int* ei = (const int*)d_in[1];
  const float* W1 = (const float*)d_in[2];
  const float* b1 = (const float*)d_in[3];
  const float* W2 = (const float*)d_in[4];
  const float* b2 = (const float*)d_in[5];
  float* out = (float*)d_out;

  const int N = in_sizes[0] / D_FEAT;
  const int E = in_sizes[1] / 2;
  const int* src = ei;
  const int* dst = ei + E;

  // workspace (4B words): [cnt: nal][off: nal][dinv: nal][btot: 1024][ssrc: Eal][h: N*64][p: N*16]
  size_t nal = ((size_t)N + 1 + 255) & ~(size_t)255;
  size_t Eal = ((size_t)E + 255) & ~(size_t)255;
  unsigned* cnt = (unsigned*)d_ws;
  unsigned* off = cnt + nal;
  float* dinv = (float*)(off + nal);
  unsigned* btot = (unsigned*)(dinv + nal);
  unsigned* ssrc = btot + 1024;
  float* h = (float*)(ssrc + Eal);
  float* p = h + (size_t)N * HID;

  int nb_N = (N + 255) / 256;
  int nb_E = (E + 255) / 256;

  // 1. CSR build + dinv
  k_zero_u32<<<nb_N, 256, 0, stream>>>(cnt, N);
  k_hist<<<nb_E, 256, 0, stream>>>(dst, cnt, E);
  k_dinv<<<nb_N, 256, 0, stream>>>(cnt, dinv, N);
  k_scan1<<<nb_N, 256, 0, stream>>>(cnt, off, btot, N);
  k_scan2<<<1, 256, 0, stream>>>(btot, nb_N);
  k_scan3<<<nb_N, 256, 0, stream>>>(off, btot, N, E);
  k_zero_u32<<<nb_N, 256, 0, stream>>>(cnt, N);  // reuse as scatter cursor
  k_scatter<<<nb_E, 256, 0, stream>>>(src, dst, off, cnt, ssrc, E);

  // 2. h = x @ W1   (LDS-staged tiles)
  k_gemm1<<<(N + BR - 1) / BR, 256, 0, stream>>>(x, W1, h, N);

  // 3+4. p = relu(D^-1/2(A+I)D^-1/2 h + b1) @ W2
  {
    long long tt = (long long)N * 64;
    k_agg1_g2<<<(unsigned)((tt + 255) / 256), 256, 0, stream>>>(h, dinv, off, ssrc, b1, W2, p, N);
  }

  // 5. out = log_softmax(D^-1/2(A+I)D^-1/2 p + b2)
  {
    long long tt = (long long)N * CLS;
    k_agg2<<<(unsigned)((tt + 255) / 256), 256, 0, stream>>>(p, dinv, off, ssrc, b2, out, N);
  }
}

// Round 5
// 757.143 us; speedup vs baseline: 2.3525x; 1.2832x over previous
//
#include <hip/hip_runtime.h>
#include <math.h>

#define D_FEAT 512
#define HID 64
#define CLS 16
#define BM 64   // rows per block in gemm1
#define BK 128  // k-chunk in gemm1

using s8v = __attribute__((ext_vector_type(8))) short;  // 8 bf16 (4 VGPRs)
using f4v = __attribute__((ext_vector_type(4))) float;  // MFMA acc

__device__ __forceinline__ unsigned short f2bf(float f) {
  unsigned u = __builtin_bit_cast(unsigned, f);
  return (unsigned short)((u + 0x7fffu + ((u >> 16) & 1u)) >> 16);  // RN-even
}

// ---------- utility ----------
__global__ __launch_bounds__(256) void k_zero_u32(unsigned* __restrict__ p, int n) {
  int i = blockIdx.x * 256 + threadIdx.x;
  if (i < n) p[i] = 0u;
}

// ---------- histogram of dst ----------
__global__ __launch_bounds__(256) void k_hist(const int* __restrict__ dst, unsigned* __restrict__ cnt, int E) {
  int e = blockIdx.x * 256 + threadIdx.x;
  if (e < E) atomicAdd(&cnt[dst[e]], 1u);
}

// ---------- dinv[i] = rsqrt(cnt[i] + 1)  (self-loop) ----------
__global__ __launch_bounds__(256) void k_dinv(const unsigned* __restrict__ cnt, float* __restrict__ dinv, int N) {
  int i = blockIdx.x * 256 + threadIdx.x;
  if (i < N) dinv[i] = rsqrtf((float)(cnt[i] + 1u));
}

// ---------- hierarchical exclusive scan ----------
__global__ __launch_bounds__(256) void k_scan1(const unsigned* __restrict__ cnt, unsigned* __restrict__ off,
                                               unsigned* __restrict__ btot, int N) {
  __shared__ unsigned wtot[4];
  const int t = threadIdx.x, wav = t >> 6, lane = t & 63;
  int i = blockIdx.x * 256 + t;
  unsigned v = (i < N) ? cnt[i] : 0u;
  unsigned xx = v;
#pragma unroll
  for (int o = 1; o < 64; o <<= 1) {
    unsigned y = __shfl_up(xx, o);
    if (lane >= o) xx += y;
  }
  if (lane == 63) wtot[wav] = xx;
  __syncthreads();
  unsigned wpre = 0, tot = 0;
#pragma unroll
  for (int w = 0; w < 4; w++) {
    unsigned tw = wtot[w];
    if (w < wav) wpre += tw;
    tot += tw;
  }
  if (i < N) off[i] = wpre + (xx - v);
  if (t == 0) btot[blockIdx.x] = tot;
}

__global__ __launch_bounds__(256) void k_scan2(unsigned* __restrict__ btot, int nb) {
  __shared__ unsigned wtot[4];
  const int t = threadIdx.x, wav = t >> 6, lane = t & 63;
  unsigned carry = 0;
  for (int base = 0; base < nb; base += 256) {
    int i = base + t;
    unsigned v = (i < nb) ? btot[i] : 0u;
    unsigned xx = v;
#pragma unroll
    for (int o = 1; o < 64; o <<= 1) {
      unsigned y = __shfl_up(xx, o);
      if (lane >= o) xx += y;
    }
    if (lane == 63) wtot[wav] = xx;
    __syncthreads();
    unsigned wpre = 0, tot = 0;
#pragma unroll
    for (int w = 0; w < 4; w++) {
      unsigned tw = wtot[w];
      if (w < wav) wpre += tw;
      tot += tw;
    }
    if (i < nb) btot[i] = carry + wpre + (xx - v);
    carry += tot;
    __syncthreads();
  }
}

__global__ __launch_bounds__(256) void k_scan3(unsigned* __restrict__ off, const unsigned* __restrict__ btot,
                                               int N, int E) {
  int i = blockIdx.x * 256 + threadIdx.x;
  if (i < N) off[i] += btot[blockIdx.x];
  if (i == 0) off[N] = (unsigned)E;
}

// ---------- scatter src into CSR order ----------
__global__ __launch_bounds__(256) void k_scatter(const int* __restrict__ src, const int* __restrict__ dst,
                                                 const unsigned* __restrict__ off, unsigned* __restrict__ cur,
                                                 unsigned* __restrict__ ssrc, int E) {
  int e = blockIdx.x * 256 + threadIdx.x;
  if (e >= E) return;
  int d = dst[e];
  unsigned pos = off[d] + atomicAdd(&cur[d], 1u);
  ssrc[pos] = (unsigned)src[e];
}

// ---------- GEMM1 (MFMA bf16): h[N][64] = x[N][512] @ W1[512][64] ----------
// 4 waves/block, 64-row tile. Wave w owns output cols [w*16, w*16+16).
// B (W1) fragments live in registers for the whole K=512 (16 k-steps x short8).
// x is staged per 128-k chunk as bf16 in LDS (+8 pad -> conflict-free ds_read_b128).
__global__ __launch_bounds__(256) void k_gemm1(const float* __restrict__ x, const float* __restrict__ W1,
                                               float* __restrict__ h, int N) {
  __shared__ __align__(16) unsigned short xa[BM][BK + 8];
  const int t = threadIdx.x;
  const int w = t >> 6, l = t & 63;
  const int lr = l & 15, lg = l >> 4;  // row-in-tile / k-group
  const int i0 = blockIdx.x * BM;
  const int n = w * 16 + lr;  // this lane's B column

  // ---- B fragments: bf16(W1[k][n]) for 16 k-steps of 32 ----
  s8v bfrag[16];
#pragma unroll
  for (int kk = 0; kk < 16; kk++) {
    s8v b;
#pragma unroll
    for (int e = 0; e < 8; e++)
      b[e] = (short)f2bf(W1[(kk * 32 + lg * 8 + e) * HID + n]);
    bfrag[kk] = b;
  }

  f4v acc[4];
#pragma unroll
  for (int mt = 0; mt < 4; mt++) acc[mt] = (f4v){0.f, 0.f, 0.f, 0.f};

#pragma unroll
  for (int c = 0; c < 4; c++) {
    // stage 64x128 f32 chunk -> bf16 LDS (each thread: 8 float4)
#pragma unroll
    for (int j = 0; j < 8; j++) {
      int f = t + 256 * j;
      int row = f >> 5, c4 = f & 31;
      int ir = i0 + row;
      if (ir >= N) ir = N - 1;
      float4 v = *reinterpret_cast<const float4*>(&x[(size_t)ir * D_FEAT + c * BK + c4 * 4]);
      uint2 pk;
      pk.x = (unsigned)f2bf(v.x) | ((unsigned)f2bf(v.y) << 16);
      pk.y = (unsigned)f2bf(v.z) | ((unsigned)f2bf(v.w) << 16);
      *reinterpret_cast<uint2*>(&xa[row][c4 * 4]) = pk;
    }
    __syncthreads();
#pragma unroll
    for (int kk = 0; kk < 4; kk++) {
#pragma unroll
      for (int mt = 0; mt < 4; mt++) {
        s8v a = *reinterpret_cast<const s8v*>(&xa[mt * 16 + lr][kk * 32 + lg * 8]);
        acc[mt] = __builtin_amdgcn_mfma_f32_16x16x32_bf16(a, bfrag[c * 4 + kk], acc[mt], 0, 0, 0);
      }
    }
    if (c < 3) __syncthreads();
  }

  // C/D layout (verified): col = lane&15, row = (lane>>4)*4 + reg
#pragma unroll
  for (int mt = 0; mt < 4; mt++) {
#pragma unroll
    for (int r = 0; r < 4; r++) {
      int ir = i0 + mt * 16 + lg * 4 + r;
      if (ir < N) h[(size_t)ir * HID + w * 16 + lr] = acc[mt][r];
    }
  }
}

// ---------- fused agg1 + bias + ReLU + GEMM2: one wave per dst node ----------
__global__ __launch_bounds__(256) void k_agg1_g2(const float* __restrict__ h, const float* __restrict__ dinv,
                                                 const unsigned* __restrict__ off, const unsigned* __restrict__ ssrc,
                                                 const float* __restrict__ b1, const float* __restrict__ W2,
                                                 float* __restrict__ p, int N) {
  __shared__ float sh[4][64];
  const int wav = threadIdx.x >> 6;
  const int lane = threadIdx.x & 63;
  const int node = (blockIdx.x * 256 + threadIdx.x) >> 6;
  const bool valid = node < N;

  float v = 0.f;
  if (valid) {
    float di = dinv[node];
    float acc = h[(size_t)node * HID + lane] * di;
    unsigned e0 = off[node], e1 = off[node + 1];
    unsigned e = e0;
    for (; e + 8 <= e1; e += 8) {
      unsigned sv[8];
      float dv[8], hv[8];
#pragma unroll
      for (int j = 0; j < 8; j++) sv[j] = ssrc[e + j];
#pragma unroll
      for (int j = 0; j < 8; j++) dv[j] = dinv[sv[j]];
#pragma unroll
      for (int j = 0; j < 8; j++) hv[j] = h[(size_t)sv[j] * HID + lane];
#pragma unroll
      for (int j = 0; j < 8; j++) acc = fmaf(hv[j], dv[j], acc);
    }
    for (; e < e1; ++e) {
      unsigned s = ssrc[e];
      acc = fmaf(h[(size_t)s * HID + lane], dinv[s], acc);
    }
    v = fmaxf(fmaf(acc, di, b1[lane]), 0.f);
  }
  sh[wav][lane] = v;
  __syncthreads();

  const int grp = lane >> 4, c = lane & 15;
  float partial = 0.f;
  const float* hv = &sh[wav][grp * 16];
#pragma unroll
  for (int k = 0; k < 16; k++) partial = fmaf(hv[k], W2[(grp * 16 + k) * CLS + c], partial);
  partial += __shfl_xor(partial, 16);
  partial += __shfl_xor(partial, 32);
  if (valid && lane < 16) p[(size_t)node * CLS + c] = partial;
}

// ---------- fused agg2 + bias + log_softmax: 16 lanes per node ----------
__global__ __launch_bounds__(256) void k_agg2(const float* __restrict__ p, const float* __restrict__ dinv,
                                              const unsigned* __restrict__ off, const unsigned* __restrict__ ssrc,
                                              const float* __restrict__ b2, float* __restrict__ out, int N) {
  int t = blockIdx.x * 256 + threadIdx.x;
  int node = t >> 4;
  int c = t & 15;
  if (node >= N) return;
  float di = dinv[node];
  float acc = p[(size_t)node * CLS + c] * di;
  unsigned e0 = off[node], e1 = off[node + 1];
  unsigned e = e0;
  for (; e + 8 <= e1; e += 8) {
    unsigned sv[8];
    float dv[8], pv[8];
#pragma unroll
    for (int j = 0; j < 8; j++) sv[j] = ssrc[e + j];
#pragma unroll
    for (int j = 0; j < 8; j++) dv[j] = dinv[sv[j]];
#pragma unroll
    for (int j = 0; j < 8; j++) pv[j] = p[(size_t)sv[j] * CLS + c];
#pragma unroll
    for (int j = 0; j < 8; j++) acc = fmaf(pv[j], dv[j], acc);
  }
  for (; e < e1; ++e) {
    unsigned s = ssrc[e];
    acc = fmaf(p[(size_t)s * CLS + c], dinv[s], acc);
  }
  float v = fmaf(acc, di, b2[c]);
  float m = v;
#pragma unroll
  for (int o = 8; o >= 1; o >>= 1) m = fmaxf(m, __shfl_xor(m, o, 16));
  float ex = expf(v - m);
  float s = ex;
#pragma unroll
  for (int o = 8; o >= 1; o >>= 1) s += __shfl_xor(s, o, 16);
  out[(size_t)node * CLS + c] = v - m - logf(s);
}

extern "C" void kernel_launch(void* const* d_in, const int* in_sizes, int n_in,
                              void* d_out, int out_size, void* d_ws, size_t ws_size,
                              hipStream_t stream) {
  const float* x = (const float*)d_in[0];
  const int* ei = (const int*)d_in[1];
  const float* W1 = (const float*)d_in[2];
  const float* b1 = (const float*)d_in[3];
  const float* W2 = (const float*)d_in[4];
  const float* b2 = (const float*)d_in[5];
  float* out = (float*)d_out;

  const int N = in_sizes[0] / D_FEAT;
  const int E = in_sizes[1] / 2;
  const int* src = ei;
  const int* dst = ei + E;

  // workspace (4B words): [cnt: nal][off: nal][dinv: nal][btot: 1024][ssrc: Eal][h: N*64][p: N*16]
  size_t nal = ((size_t)N + 1 + 255) & ~(size_t)255;
  size_t Eal = ((size_t)E + 255) & ~(size_t)255;
  unsigned* cnt = (unsigned*)d_ws;
  unsigned* off = cnt + nal;
  float* dinv = (float*)(off + nal);
  unsigned* btot = (unsigned*)(dinv + nal);
  unsigned* ssrc = btot + 1024;
  float* h = (float*)(ssrc + Eal);
  float* p = h + (size_t)N * HID;

  int nb_N = (N + 255) / 256;
  int nb_E = (E + 255) / 256;

  // 1. CSR build + dinv
  k_zero_u32<<<nb_N, 256, 0, stream>>>(cnt, N);
  k_hist<<<nb_E, 256, 0, stream>>>(dst, cnt, E);
  k_dinv<<<nb_N, 256, 0, stream>>>(cnt, dinv, N);
  k_scan1<<<nb_N, 256, 0, stream>>>(cnt, off, btot, N);
  k_scan2<<<1, 256, 0, stream>>>(btot, nb_N);
  k_scan3<<<nb_N, 256, 0, stream>>>(off, btot, N, E);
  k_zero_u32<<<nb_N, 256, 0, stream>>>(cnt, N);  // reuse as scatter cursor
  k_scatter<<<nb_E, 256, 0, stream>>>(src, dst, off, cnt, ssrc, E);

  // 2. h = x @ W1   (MFMA bf16, f32 accumulate)
  k_gemm1<<<(N + BM - 1) / BM, 256, 0, stream>>>(x, W1, h, N);

  // 3+4. p = relu(D^-1/2(A+I)D^-1/2 h + b1) @ W2
  {
    long long tt = (long long)N * 64;
    k_agg1_g2<<<(unsigned)((tt + 255) / 256), 256, 0, stream>>>(h, dinv, off, ssrc, b1, W2, p, N);
  }

  // 5. out = log_softmax(D^-1/2(A+I)D^-1/2 p + b2)
  {
    long long tt = (long long)N * CLS;
    k_agg2<<<(unsigned)((tt + 255) / 256), 256, 0, stream>>>(p, dinv, off, ssrc, b2, out, N);
  }
}

// Round 6
// 585.449 us; speedup vs baseline: 3.0424x; 1.2933x over previous
//
#include <hip/hip_runtime.h>
#include <math.h>

#define D_FEAT 512
#define HID 64
#define CLS 16
#define BM 64    // rows per block in gemm1
#define BK 128   // k-chunk in gemm1
#define EPB 4096 // edges per block in k_part

using s8v = __attribute__((ext_vector_type(8))) short;  // 8 bf16 (4 VGPRs)
using f4v = __attribute__((ext_vector_type(4))) float;  // MFMA acc
typedef unsigned long long u64;

__device__ __forceinline__ unsigned short f2bf(float f) {
  unsigned u = __builtin_bit_cast(unsigned, f);
  return (unsigned short)((u + 0x7fffu + ((u >> 16) & 1u)) >> 16);  // RN-even
}

// ---------- utility ----------
__global__ __launch_bounds__(256) void k_zero_u32(unsigned* __restrict__ p, int n) {
  int i = blockIdx.x * 256 + threadIdx.x;
  if (i < n) p[i] = 0u;
}

// ---------- 256-node-bucket histogram of dst (LDS-aggregated) ----------
__global__ __launch_bounds__(256) void k_bhist(const int* __restrict__ dst, unsigned* __restrict__ bcnt, int E) {
  __shared__ unsigned sc[512];
  const int t = threadIdx.x;
  for (int i = t; i < 512; i += 256) sc[i] = 0u;
  __syncthreads();
  for (int e = blockIdx.x * 256 + t; e < E; e += gridDim.x * 256)
    atomicAdd(&sc[dst[e] >> 8], 1u);
  __syncthreads();
  for (int i = t; i < 512; i += 256)
    if (sc[i]) atomicAdd(&bcnt[i], sc[i]);
}

// ---------- scan buckets in place (exclusive); write sentinels ----------
__global__ __launch_bounds__(256) void k_bscan(unsigned* __restrict__ bb, unsigned* __restrict__ off,
                                               int NB, int N, int E) {
  __shared__ unsigned wtot[4];
  const int t = threadIdx.x, wav = t >> 6, lane = t & 63;
  unsigned carry = 0;
  for (int base = 0; base < NB; base += 256) {
    int i = base + t;
    unsigned v = (i < NB) ? bb[i] : 0u;
    unsigned xx = v;
#pragma unroll
    for (int o = 1; o < 64; o <<= 1) {
      unsigned y = __shfl_up(xx, o);
      if (lane >= o) xx += y;
    }
    if (lane == 63) wtot[wav] = xx;
    __syncthreads();
    unsigned wpre = 0, tot = 0;
#pragma unroll
    for (int w = 0; w < 4; w++) {
      unsigned tw = wtot[w];
      if (w < wav) wpre += tw;
      tot += tw;
    }
    if (i < NB) bb[i] = carry + wpre + (xx - v);
    carry += tot;
    __syncthreads();
  }
  if (t == 0) {
    bb[NB] = (unsigned)E;
    off[N] = (unsigned)E;
  }
}

// ---------- partition edges into bucket runs of (dst,src) pairs ----------
__global__ __launch_bounds__(256) void k_part(const int* __restrict__ src, const int* __restrict__ dst,
                                              const unsigned* __restrict__ bb, unsigned* __restrict__ gcur,
                                              u64* __restrict__ pairs, int E, int NB) {
  __shared__ unsigned cnt[512], lbase[512];
  const int t = threadIdx.x;
  const int e0 = blockIdx.x * EPB;
  for (int i = t; i < 512; i += 256) cnt[i] = 0u;
  __syncthreads();
  int d[16], s[16];
#pragma unroll
  for (int j = 0; j < 16; j++) {
    int e = e0 + j * 256 + t;
    if (e < E) {
      d[j] = dst[e];
      s[j] = src[e];
      atomicAdd(&cnt[d[j] >> 8], 1u);
    } else
      d[j] = -1;
  }
  __syncthreads();
  for (int b = t; b < NB; b += 256) {
    unsigned c = cnt[b];
    lbase[b] = c ? bb[b] + atomicAdd(&gcur[b], c) : 0u;
  }
  __syncthreads();
  for (int i = t; i < 512; i += 256) cnt[i] = 0u;  // reuse as cursor
  __syncthreads();
#pragma unroll
  for (int j = 0; j < 16; j++) {
    if (d[j] >= 0) {
      int b = d[j] >> 8;
      unsigned r = atomicAdd(&cnt[b], 1u);
      pairs[lbase[b] + r] = ((u64)(unsigned)d[j] << 32) | (unsigned)s[j];
    }
  }
}

// ---------- per-bucket CSR finalize: counts, scan, off/dinv, place ssrc ----------
__global__ __launch_bounds__(256) void k_csr(const u64* __restrict__ pairs, const unsigned* __restrict__ bb,
                                             unsigned* __restrict__ off, float* __restrict__ dinv,
                                             unsigned* __restrict__ ssrc, int N) {
  __shared__ unsigned scnt[256], soff[256];
  __shared__ unsigned wtot[4];
  const int t = threadIdx.x, wav = t >> 6, lane = t & 63;
  const int b = blockIdx.x;
  const unsigned n0 = (unsigned)b << 8;
  const unsigned r0 = bb[b], r1 = bb[b + 1];
  scnt[t] = 0u;
  __syncthreads();
  for (unsigned i = r0 + t; i < r1; i += 256) {
    unsigned ln = (unsigned)(pairs[i] >> 32) - n0;
    atomicAdd(&scnt[ln], 1u);
  }
  __syncthreads();
  unsigned v = scnt[t], xx = v;
#pragma unroll
  for (int o = 1; o < 64; o <<= 1) {
    unsigned y = __shfl_up(xx, o);
    if (lane >= o) xx += y;
  }
  if (lane == 63) wtot[wav] = xx;
  __syncthreads();
  unsigned wpre = 0;
#pragma unroll
  for (int w = 0; w < 4; w++)
    if (w < wav) wpre += wtot[w];
  unsigned excl = wpre + xx - v;
  soff[t] = excl;
  int node = (int)n0 + t;
  if (node < N) {
    off[node] = r0 + excl;
    dinv[node] = rsqrtf((float)(v + 1u));
  }
  __syncthreads();
  scnt[t] = 0u;  // reuse as cursor
  __syncthreads();
  for (unsigned i = r0 + t; i < r1; i += 256) {
    u64 pr = pairs[i];
    unsigned ln = (unsigned)(pr >> 32) - n0;
    unsigned r = atomicAdd(&scnt[ln], 1u);
    ssrc[r0 + soff[ln] + r] = (unsigned)pr;
  }
}

// ---------- GEMM1 (MFMA bf16, pipelined staging): h[N][64] = x[N][512] @ W1[512][64] ----------
__global__ __launch_bounds__(256) void k_gemm1(const float* __restrict__ x, const float* __restrict__ W1,
                                               float* __restrict__ h, int N) {
  __shared__ __align__(16) unsigned short xa[BM][BK + 8];
  const int t = threadIdx.x;
  const int w = t >> 6, l = t & 63;
  const int lr = l & 15, lg = l >> 4;
  const int i0 = blockIdx.x * BM;
  const int n = w * 16 + lr;

  // B fragments in registers for all of K
  s8v bfrag[16];
#pragma unroll
  for (int kk = 0; kk < 16; kk++) {
    s8v b;
#pragma unroll
    for (int e = 0; e < 8; e++) b[e] = (short)f2bf(W1[(kk * 32 + lg * 8 + e) * HID + n]);
    bfrag[kk] = b;
  }

  // staging addresses for this thread (8 float4 per chunk)
  const int srow = t >> 5, sc4 = t & 31;  // via f = t + 256*j: row = f>>5, c4 = f&31
  float4 xr[8];
#pragma unroll
  for (int j = 0; j < 8; j++) {
    int f = t + 256 * j;
    int row = f >> 5, c4 = f & 31;
    int ir = i0 + row;
    if (ir >= N) ir = N - 1;
    xr[j] = *reinterpret_cast<const float4*>(&x[(size_t)ir * D_FEAT + 0 * BK + c4 * 4]);
  }

  f4v acc[4];
#pragma unroll
  for (int mt = 0; mt < 4; mt++) acc[mt] = (f4v){0.f, 0.f, 0.f, 0.f};

#pragma unroll
  for (int c = 0; c < 4; c++) {
    // write staged regs -> LDS (bf16)
#pragma unroll
    for (int j = 0; j < 8; j++) {
      int f = t + 256 * j;
      int row = f >> 5, c4 = f & 31;
      uint2 pk;
      pk.x = (unsigned)f2bf(xr[j].x) | ((unsigned)f2bf(xr[j].y) << 16);
      pk.y = (unsigned)f2bf(xr[j].z) | ((unsigned)f2bf(xr[j].w) << 16);
      *reinterpret_cast<uint2*>(&xa[row][c4 * 4]) = pk;
    }
    __syncthreads();
    // issue next chunk's loads (overlap with MFMA below)
    if (c < 3) {
#pragma unroll
      for (int j = 0; j < 8; j++) {
        int f = t + 256 * j;
        int row = f >> 5, c4 = f & 31;
        int ir = i0 + row;
        if (ir >= N) ir = N - 1;
        xr[j] = *reinterpret_cast<const float4*>(&x[(size_t)ir * D_FEAT + (c + 1) * BK + c4 * 4]);
      }
    }
#pragma unroll
    for (int kk = 0; kk < 4; kk++) {
#pragma unroll
      for (int mt = 0; mt < 4; mt++) {
        s8v a = *reinterpret_cast<const s8v*>(&xa[mt * 16 + lr][kk * 32 + lg * 8]);
        acc[mt] = __builtin_amdgcn_mfma_f32_16x16x32_bf16(a, bfrag[c * 4 + kk], acc[mt], 0, 0, 0);
      }
    }
    if (c < 3) __syncthreads();
  }

  // C/D layout: col = lane&15, row = (lane>>4)*4 + reg
#pragma unroll
  for (int mt = 0; mt < 4; mt++) {
#pragma unroll
    for (int r = 0; r < 4; r++) {
      int ir = i0 + mt * 16 + lg * 4 + r;
      if (ir < N) h[(size_t)ir * HID + w * 16 + lr] = acc[mt][r];
    }
  }
  (void)srow; (void)sc4;
}

// ---------- fused agg1 + bias + ReLU + GEMM2: one wave per dst node ----------
__global__ __launch_bounds__(256) void k_agg1_g2(const float* __restrict__ h, const float* __restrict__ dinv,
                                                 const unsigned* __restrict__ off, const unsigned* __restrict__ ssrc,
                                                 const float* __restrict__ b1, const float* __restrict__ W2,
                                                 float* __restrict__ p, int N) {
  __shared__ float sh[4][64];
  const int wav = threadIdx.x >> 6;
  const int lane = threadIdx.x & 63;
  const int node = (blockIdx.x * 256 + threadIdx.x) >> 6;
  const bool valid = node < N;

  float v = 0.f;
  if (valid) {
    float di = dinv[node];
    float acc = h[(size_t)node * HID + lane] * di;
    unsigned e0 = off[node], e1 = off[node + 1];
    unsigned e = e0;
    for (; e + 8 <= e1; e += 8) {
      unsigned sv[8];
      float dv[8], hv[8];
#pragma unroll
      for (int j = 0; j < 8; j++) sv[j] = ssrc[e + j];
#pragma unroll
      for (int j = 0; j < 8; j++) dv[j] = dinv[sv[j]];
#pragma unroll
      for (int j = 0; j < 8; j++) hv[j] = h[(size_t)sv[j] * HID + lane];
#pragma unroll
      for (int j = 0; j < 8; j++) acc = fmaf(hv[j], dv[j], acc);
    }
    for (; e < e1; ++e) {
      unsigned s = ssrc[e];
      acc = fmaf(h[(size_t)s * HID + lane], dinv[s], acc);
    }
    v = fmaxf(fmaf(acc, di, b1[lane]), 0.f);
  }
  sh[wav][lane] = v;
  __syncthreads();

  const int grp = lane >> 4, c = lane & 15;
  float partial = 0.f;
  const float* hv = &sh[wav][grp * 16];
#pragma unroll
  for (int k = 0; k < 16; k++) partial = fmaf(hv[k], W2[(grp * 16 + k) * CLS + c], partial);
  partial += __shfl_xor(partial, 16);
  partial += __shfl_xor(partial, 32);
  if (valid && lane < 16) p[(size_t)node * CLS + c] = partial;
}

// ---------- fused agg2 + bias + log_softmax: 16 lanes per node ----------
__global__ __launch_bounds__(256) void k_agg2(const float* __restrict__ p, const float* __restrict__ dinv,
                                              const unsigned* __restrict__ off, const unsigned* __restrict__ ssrc,
                                              const float* __restrict__ b2, float* __restrict__ out, int N) {
  int t = blockIdx.x * 256 + threadIdx.x;
  int node = t >> 4;
  int c = t & 15;
  if (node >= N) return;
  float di = dinv[node];
  float acc = p[(size_t)node * CLS + c] * di;
  unsigned e0 = off[node], e1 = off[node + 1];
  unsigned e = e0;
  for (; e + 8 <= e1; e += 8) {
    unsigned sv[8];
    float dv[8], pv[8];
#pragma unroll
    for (int j = 0; j < 8; j++) sv[j] = ssrc[e + j];
#pragma unroll
    for (int j = 0; j < 8; j++) dv[j] = dinv[sv[j]];
#pragma unroll
    for (int j = 0; j < 8; j++) pv[j] = p[(size_t)sv[j] * CLS + c];
#pragma unroll
    for (int j = 0; j < 8; j++) acc = fmaf(pv[j], dv[j], acc);
  }
  for (; e < e1; ++e) {
    unsigned s = ssrc[e];
    acc = fmaf(p[(size_t)s * CLS + c], dinv[s], acc);
  }
  float v = fmaf(acc, di, b2[c]);
  float m = v;
#pragma unroll
  for (int o = 8; o >= 1; o >>= 1) m = fmaxf(m, __shfl_xor(m, o, 16));
  float ex = expf(v - m);
  float s = ex;
#pragma unroll
  for (int o = 8; o >= 1; o >>= 1) s += __shfl_xor(s, o, 16);
  out[(size_t)node * CLS + c] = v - m - logf(s);
}

extern "C" void kernel_launch(void* const* d_in, const int* in_sizes, int n_in,
                              void* d_out, int out_size, void* d_ws, size_t ws_size,
                              hipStream_t stream) {
  const float* x = (const float*)d_in[0];
  const int* ei = (const int*)d_in[1];
  const float* W1 = (const float*)d_in[2];
  const float* b1 = (const float*)d_in[3];
  const float* W2 = (const float*)d_in[4];
  const float* b2 = (const float*)d_in[5];
  float* out = (float*)d_out;

  const int N = in_sizes[0] / D_FEAT;
  const int E = in_sizes[1] / 2;
  const int* src = ei;
  const int* dst = ei + E;
  const int NB = (N + 255) >> 8;  // 256-node buckets (<= 512 for N <= 131072)

  // workspace (4B words):
  // [off: nal][dinv: nal][bb: 1024][gcur: 1024][ssrc: Eal][h: max(N*64, E*2)][p: N*16]
  // pairs (u64, E entries) overlays h: dead before gemm1 writes h.
  size_t nal = ((size_t)N + 1 + 255) & ~(size_t)255;
  size_t Eal = ((size_t)E + 255) & ~(size_t)255;
  unsigned* off = (unsigned*)d_ws;
  float* dinv = (float*)(off + nal);
  unsigned* bb = (unsigned*)(dinv + nal);
  unsigned* gcur = bb + 1024;
  unsigned* ssrc = gcur + 1024;
  float* h = (float*)(ssrc + Eal);
  u64* pairs = (u64*)h;
  size_t hwords = (size_t)N * HID;
  size_t pwords = (size_t)E * 2;
  float* p = h + (hwords > pwords ? hwords : pwords);

  // 1. CSR build: bucket hist -> scan -> partition -> per-bucket finalize
  k_zero_u32<<<8, 256, 0, stream>>>(bb, 2048);  // zero bb + gcur
  k_bhist<<<256, 256, 0, stream>>>(dst, bb, E);
  k_bscan<<<1, 256, 0, stream>>>(bb, off, NB, N, E);
  k_part<<<(E + EPB - 1) / EPB, 256, 0, stream>>>(src, dst, bb, gcur, pairs, E, NB);
  k_csr<<<NB, 256, 0, stream>>>(pairs, bb, off, dinv, ssrc, N);

  // 2. h = x @ W1   (MFMA bf16, pipelined staging)
  k_gemm1<<<(N + BM - 1) / BM, 256, 0, stream>>>(x, W1, h, N);

  // 3+4. p = relu(D^-1/2(A+I)D^-1/2 h + b1) @ W2
  {
    long long tt = (long long)N * 64;
    k_agg1_g2<<<(unsigned)((tt + 255) / 256), 256, 0, stream>>>(h, dinv, off, ssrc, b1, W2, p, N);
  }

  // 5. out = log_softmax(D^-1/2(A+I)D^-1/2 p + b2)
  {
    long long tt = (long long)N * CLS;
    k_agg2<<<(unsigned)((tt + 255) / 256), 256, 0, stream>>>(p, dinv, off, ssrc, b2, out, N);
  }
}